// Round 1
// baseline (300.412 us; speedup 1.0000x reference)
//
#include <hip/hip_runtime.h>

#define BB 4
#define NN 4096
#define DD 64
#define KK 16

// ws float offsets
#define OFF_EMB   0u          // B*N*D = 1048576
#define OFF_SIMT  1048576u    // B*K*N = 262144  (layout [b][k][n])
#define OFF_NRM2  1310720u    // B*N   = 16384
#define OFF_FCSUM 1327104u    // B*K*D = 4096
#define OFF_GCSUM 1331200u    // B*K*3 = 192
#define OFF_CNT   1331392u    // B*K   = 64
#define OFF_FC    1331456u    // 4096
#define OFF_CEN   1335552u    // 4096
#define OFF_GC    1339648u    // 192
#define OFF_FCN2  1339840u    // 64
#define OFF_FCN   1339904u    // 64
#define OFF_CEN2  1339968u    // 64
#define OFF_GC2   1340032u    // 64
#define OFF_ACC   1340096u    // 8 doubles (16 floats), 8B aligned
// acc: 0 var, 1 dist, 2 reg, 3 center, 4 boundary(raw upper-pair sum), 5 lovasz

__device__ __forceinline__ float blockReduceSum(float v, float* sbuf){
  int t = threadIdx.x;
  #pragma unroll
  for (int off = 32; off > 0; off >>= 1) v += __shfl_xor(v, off, 64);
  if ((t & 63) == 0) sbuf[t >> 6] = v;
  __syncthreads();
  float s = 0.f;
  if (t == 0){
    int nw = blockDim.x >> 6;
    for (int i = 0; i < nw; i++) s += sbuf[i];
  }
  __syncthreads();
  return s;
}

__global__ void kinit(float* ws){
  int t = blockIdx.x * blockDim.x + threadIdx.x;
  int stride = blockDim.x * gridDim.x;
  for (int i = t; i < 4352; i += stride) ws[OFF_FCSUM + i] = 0.f;
  for (int i = t; i < 16;   i += stride) ws[OFF_ACC + i]   = 0.f;
}

// Normalize embeddings, compute per-instance sums (fc numerator, gc numerator, counts).
// One wave handles 16 points sequentially; lane = feature dim.
__global__ void knormacc(const float* __restrict__ emb, const float* __restrict__ pts,
                         const int* __restrict__ lbl, float* __restrict__ ws){
  __shared__ float fcl[KK * DD];
  __shared__ float gcl[KK * 3];
  __shared__ float cntl[KK];
  int t = threadIdx.x;
  for (int i = t; i < KK * DD; i += 256) fcl[i] = 0.f;
  if (t < KK * 3) gcl[t] = 0.f;
  if (t < KK) cntl[t] = 0.f;
  __syncthreads();

  int lane = t & 63, w = t >> 6;
  int b = blockIdx.x >> 6;              // 64 blocks per batch
  int local = blockIdx.x & 63;          // covers 64 points per block
  int base = local * 64 + w * 16;
  const float* E = emb + (size_t)b * NN * DD;
  float* EN = ws + OFF_EMB + (size_t)b * NN * DD;

  for (int i = 0; i < 16; i++){
    int n = base + i;
    float v = E[(size_t)n * DD + lane];
    float ss = v * v;
    #pragma unroll
    for (int off = 1; off < 64; off <<= 1) ss += __shfl_xor(ss, off, 64);
    float nrm = sqrtf(ss);
    float scale = 1.0f / fmaxf(nrm, 1e-12f);
    float vn = v * scale;
    EN[(size_t)n * DD + lane] = vn;
    if (lane == 0) ws[OFF_NRM2 + b * NN + n] = ss * scale * scale;
    int l = lbl[b * NN + n];
    if (l >= 1 && l <= KK){
      int k = l - 1;
      atomicAdd(&fcl[k * DD + lane], vn);
      if (lane < 3) atomicAdd(&gcl[k * 3 + lane], pts[((size_t)b * NN + n) * 3 + lane]);
      if (lane == 0) atomicAdd(&cntl[k], 1.0f);
    }
  }
  __syncthreads();
  for (int i = t; i < KK * DD; i += 256) atomicAdd(&ws[OFF_FCSUM + b * KK * DD + i], fcl[i]);
  if (t < KK * 3) atomicAdd(&ws[OFF_GCSUM + b * KK * 3 + t], gcl[t]);
  if (t < KK)     atomicAdd(&ws[OFF_CNT + b * KK + t], cntl[t]);
}

// Finalize centers, dist loss, reg loss. One block per batch.
__global__ void kcenters(float* __restrict__ ws, double* __restrict__ acc){
  __shared__ float cenS[KK * DD];
  __shared__ float cen2S[KK];
  __shared__ float red[4];
  int b = blockIdx.x, t = threadIdx.x;
  if (t < KK){
    int k = t;
    float c = ws[OFF_CNT + b * KK + k];
    float inv_c = 1.f / c;
    float n2 = 0.f;
    #pragma unroll
    for (int d = 0; d < DD; d++){
      float f = ws[OFF_FCSUM + (b * KK + k) * DD + d] * inv_c;
      ws[OFF_FC + (b * KK + k) * DD + d] = f;
      n2 += f * f;
    }
    float fn = sqrtf(n2);
    ws[OFF_FCN2 + b * KK + k] = n2;
    ws[OFF_FCN + b * KK + k] = fn;
    float inv = 1.f / fmaxf(fn, 1e-12f);
    float c2 = 0.f;
    #pragma unroll
    for (int d = 0; d < DD; d++){
      float ce = ws[OFF_FC + (b * KK + k) * DD + d] * inv;
      ws[OFF_CEN + (b * KK + k) * DD + d] = ce;
      cenS[k * DD + d] = ce;
      c2 += ce * ce;
    }
    ws[OFF_CEN2 + b * KK + k] = c2;
    cen2S[k] = c2;
    float g2 = 0.f;
    for (int j = 0; j < 3; j++){
      float g = ws[OFF_GCSUM + (b * KK + k) * 3 + j] * inv_c;
      ws[OFF_GC + (b * KK + k) * 3 + j] = g;
      g2 += g * g;
    }
    ws[OFF_GC2 + b * KK + k] = g2;
  }
  __syncthreads();
  int i = t >> 4, j = t & 15;
  float v = 0.f;
  if (i != j){
    float dot = 0.f;
    #pragma unroll
    for (int d = 0; d < DD; d++) dot += cenS[i * DD + d] * cenS[j * DD + d];
    float cd = sqrtf(fmaxf(cen2S[i] + cen2S[j] - 2.f * dot, 0.f));
    v = fmaxf(3.f - cd, 0.f);
  }
  float s = blockReduceSum(v, red);
  if (t == 0){
    atomicAdd(&acc[1], (double)(s / 240.f));
    float s2 = 0.f;
    for (int k = 0; k < KK; k++) s2 += cen2S[k];
    atomicAdd(&acc[2], (double)(sqrtf(s2) * 0.001f));
  }
}

// Per-point: sims for lovasz, var loss, center loss. Thread per point.
__global__ void kperpoint(const float* __restrict__ pts, const int* __restrict__ lbl,
                          float* __restrict__ ws, double* __restrict__ acc){
  __shared__ float4 fcl4[KK][16];
  __shared__ float fcnS[KK], fcn2S[KK], cen2S[KK], cntS[KK], invS[KK], gc2S[KK];
  __shared__ float gcS[KK][3];
  __shared__ float red[4];
  int t = threadIdx.x;
  int b = blockIdx.x >> 4;
  int n = (blockIdx.x & 15) * 256 + t;
  for (int i = t; i < KK * DD; i += 256) ((float*)fcl4)[i] = ws[OFF_FC + b * KK * DD + i];
  if (t < KK){
    float fn = ws[OFF_FCN + b * KK + t];
    fcnS[t] = fn;
    fcn2S[t] = ws[OFF_FCN2 + b * KK + t];
    cen2S[t] = ws[OFF_CEN2 + b * KK + t];
    cntS[t] = ws[OFF_CNT + b * KK + t];
    invS[t] = 1.f / fmaxf(fn, 1e-12f);
    gc2S[t] = ws[OFF_GC2 + b * KK + t];
    gcS[t][0] = ws[OFF_GC + (b * KK + t) * 3 + 0];
    gcS[t][1] = ws[OFF_GC + (b * KK + t) * 3 + 1];
    gcS[t][2] = ws[OFF_GC + (b * KK + t) * 3 + 2];
  }
  __syncthreads();

  const float* EN = ws + OFF_EMB + ((size_t)(b * NN + n)) * DD;
  float4 v[16];
  #pragma unroll
  for (int i = 0; i < 16; i++) v[i] = *(const float4*)&EN[i * 4];
  float nrm2 = ws[OFF_NRM2 + b * NN + n];
  float nrm = sqrtf(nrm2);
  int l = lbl[b * NN + n];
  float p0 = pts[((size_t)b * NN + n) * 3 + 0];
  float p1 = pts[((size_t)b * NN + n) * 3 + 1];
  float p2 = pts[((size_t)b * NN + n) * 3 + 2];
  float p2sum = p0 * p0 + p1 * p1 + p2 * p2;
  float varA = 0.f, cenA = 0.f;

  for (int k = 0; k < KK; k++){
    float dot = 0.f;
    #pragma unroll
    for (int i = 0; i < 16; i++){
      float4 f = fcl4[k][i];
      dot += v[i].x * f.x + v[i].y * f.y + v[i].z * f.z + v[i].w * f.w;
    }
    float sim = dot / (fmaxf(nrm, 1e-8f) * fmaxf(fcnS[k], 1e-8f));
    ws[OFF_SIMT + (size_t)(b * KK + k) * NN + n] = sim;
    if (l == k + 1){
      float dotc = dot * invS[k];
      float dnc = sqrtf(fmaxf(nrm2 + cen2S[k] - 2.f * dotc, 0.f));
      varA += fmaxf(dnc - 0.5f, 0.f) / cntS[k];
      float fd = sqrtf(fmaxf(nrm2 + fcn2S[k] - 2.f * dot, 0.f));
      float gd2 = p2sum + gc2S[k] - 2.f * (p0 * gcS[k][0] + p1 * gcS[k][1] + p2 * gcS[k][2]);
      float sd = sqrtf(fmaxf(gd2, 0.f));
      cenA += sd * fd / cntS[k];
    }
  }
  float vs = blockReduceSum(varA, red);
  if (t == 0) atomicAdd(&acc[0], (double)vs);
  float cs = blockReduceSum(cenA, red);
  if (t == 0) atomicAdd(&acc[3], (double)cs);
}

// Boundary loss: strictly-upper pairs via 128x128 tiles over the gram matrix.
#define TS 128
#define LDST 68
__global__ __launch_bounds__(256, 2) void kboundary(const int* __restrict__ lbl,
                                                    float* __restrict__ ws,
                                                    double* __restrict__ acc){
  __shared__ float As[TS * LDST];
  __shared__ float Bs[TS * LDST];
  __shared__ int lA[TS], lB[TS];
  __shared__ float nA[TS], nB[TS];
  __shared__ float red[4];
  int t = threadIdx.x;
  int b = blockIdx.y;
  int rem = blockIdx.x, ti = 0;
  while (rem >= 32 - ti){ rem -= 32 - ti; ti++; }
  int tj = ti + rem;
  const float* E = ws + OFF_EMB + (size_t)b * NN * DD;

  #pragma unroll
  for (int q = 0; q < 8; q++){
    int l4 = t + q * 256;
    int row = l4 >> 4, c4 = l4 & 15;
    float4 va = *(const float4*)&E[(size_t)(ti * TS + row) * DD + c4 * 4];
    *(float4*)&As[row * LDST + c4 * 4] = va;
    float4 vb = *(const float4*)&E[(size_t)(tj * TS + row) * DD + c4 * 4];
    *(float4*)&Bs[row * LDST + c4 * 4] = vb;
  }
  if (t < TS){
    lA[t] = lbl[b * NN + ti * TS + t];
    nA[t] = ws[OFF_NRM2 + b * NN + ti * TS + t];
  } else if (t < 2 * TS){
    int u = t - TS;
    lB[u] = lbl[b * NN + tj * TS + u];
    nB[u] = ws[OFF_NRM2 + b * NN + tj * TS + u];
  }
  __syncthreads();

  int tx = t & 15, ty = t >> 4;
  float accr[8][8];
  #pragma unroll
  for (int r = 0; r < 8; r++)
    #pragma unroll
    for (int c = 0; c < 8; c++) accr[r][c] = 0.f;

  for (int k = 0; k < DD; k += 4){
    float4 a4[8], b4[8];
    #pragma unroll
    for (int r = 0; r < 8; r++) a4[r] = *(const float4*)&As[(ty + 16 * r) * LDST + k];
    #pragma unroll
    for (int c = 0; c < 8; c++) b4[c] = *(const float4*)&Bs[(tx + 16 * c) * LDST + k];
    #pragma unroll
    for (int r = 0; r < 8; r++)
      #pragma unroll
      for (int c = 0; c < 8; c++)
        accr[r][c] += a4[r].x * b4[c].x + a4[r].y * b4[c].y
                    + a4[r].z * b4[c].z + a4[r].w * b4[c].w;
  }

  float sum = 0.f;
  #pragma unroll
  for (int r = 0; r < 8; r++){
    int ia = ty + 16 * r;
    int gi = ti * TS + ia;
    #pragma unroll
    for (int c = 0; c < 8; c++){
      int ib = tx + 16 * c;
      int gj = tj * TS + ib;
      if (gi < gj){
        float d2 = nA[ia] + nB[ib] - 2.f * accr[r][c];
        float d = sqrtf(fmaxf(d2, 0.f));
        float f = (lA[ia] == lB[ib]) ? 1.5f : fmaxf(1.5f - d, 0.f);
        sum += f;
      }
    }
  }
  float s = blockReduceSum(sum, red);
  if (t == 0) atomicAdd(&acc[4], (double)s);
}

// Lovasz: one block per (b,k). Bitonic sort of (desc_sim_bits, idx) u64 keys in LDS.
__global__ void klovasz(const int* __restrict__ lbl, float* __restrict__ ws,
                        double* __restrict__ acc){
  __shared__ unsigned long long key[NN];
  __shared__ int psum[256];
  __shared__ float red[4];
  int t = threadIdx.x;
  int bk = blockIdx.x;
  int b = bk >> 4, k = bk & 15;
  const float* sim = ws + OFF_SIMT + (size_t)bk * NN;

  for (int j = 0; j < 16; j++){
    int n = t + j * 256;
    unsigned u = __float_as_uint(sim[n]);
    unsigned asc = (u & 0x80000000u) ? ~u : (u | 0x80000000u);
    key[n] = ((unsigned long long)(~asc) << 32) | (unsigned)n;
  }
  __syncthreads();

  for (int size = 2; size <= NN; size <<= 1){
    for (int stride = size >> 1; stride > 0; stride >>= 1){
      #pragma unroll 1
      for (int j = 0; j < 16; j++){
        int i = t + j * 256;
        int p = i ^ stride;
        if (p > i){
          unsigned long long a = key[i], c = key[p];
          bool sw = ((i & size) == 0) ? (a > c) : (a < c);
          if (sw){ key[i] = c; key[p] = a; }
        }
      }
      __syncthreads();
    }
  }

  float cntk = ws[OFF_CNT + b * KK + k];
  int c0 = t * 16;
  int local = 0;
  for (int q = 0; q < 16; q++){
    int idx = (int)(unsigned)key[c0 + q];
    if (lbl[b * NN + idx] == k + 1) local++;
  }
  psum[t] = local;
  __syncthreads();
  for (int off = 1; off < 256; off <<= 1){
    int add = (t >= off) ? psum[t - off] : 0;
    __syncthreads();
    psum[t] += add;
    __syncthreads();
  }
  int base = psum[t] - local;

  float csum = (float)base;
  float jprev;
  if (c0 == 0) jprev = 0.f;
  else {
    float inter = cntk - (float)base;
    float uni = cntk + (float)c0 - (float)base;
    jprev = 1.f - inter / uni;
  }
  float lsum = 0.f;
  for (int q = 0; q < 16; q++){
    int i = c0 + q;
    unsigned long long kk = key[i];
    int idx = (int)(unsigned)kk;
    float m = (lbl[b * NN + idx] == k + 1) ? 1.f : 0.f;
    unsigned asc = ~((unsigned)(kk >> 32));
    unsigned u = (asc & 0x80000000u) ? (asc ^ 0x80000000u) : ~asc;
    float ss = __uint_as_float(u);
    csum += m;
    float inter = cntk - csum;
    float uni = cntk + (float)(i + 1) - csum;
    float jac = 1.f - inter / uni;
    lsum += fmaxf(ss, 0.f) * (jac - jprev);
    jprev = jac;
  }
  float tot = blockReduceSum(lsum, red);
  if (t == 0) atomicAdd(&acc[5], (double)tot);
}

__global__ void kfinal(const double* __restrict__ acc, float* __restrict__ out){
  if (threadIdx.x == 0 && blockIdx.x == 0){
    double var_l  = acc[0] / (4.0 + 1e-6);
    double dist_l = acc[1] / (4.0 + 1e-6);
    double reg_l  = acc[2] / (4.0 + 1e-6);
    double cen_l  = acc[3] / 4.0;
    double bnd_l  = (2.0 * acc[4] + 1.5 * (double)NN * BB) / ((double)NN * NN * BB);
    double lov_l  = acc[5] / 4.0;
    double total = 0.1 * (var_l + dist_l + reg_l) + 0.1 * cen_l + 0.05 * bnd_l + 0.01 * lov_l;
    out[0] = (float)total; out[1] = (float)var_l; out[2] = (float)dist_l;
    out[3] = (float)reg_l; out[4] = (float)cen_l; out[5] = (float)bnd_l;
    out[6] = (float)lov_l;
  }
}

extern "C" void kernel_launch(void* const* d_in, const int* in_sizes, int n_in,
                              void* d_out, int out_size, void* d_ws, size_t ws_size,
                              hipStream_t stream){
  const float* pts = (const float*)d_in[0];
  const float* emb = (const float*)d_in[1];
  const int* lbl   = (const int*)d_in[2];
  float* out = (float*)d_out;
  float* ws = (float*)d_ws;
  double* acc = (double*)(ws + OFF_ACC);

  hipLaunchKernelGGL(kinit,     dim3(4),        dim3(256), 0, stream, ws);
  hipLaunchKernelGGL(knormacc,  dim3(256),      dim3(256), 0, stream, emb, pts, lbl, ws);
  hipLaunchKernelGGL(kcenters,  dim3(BB),       dim3(256), 0, stream, ws, acc);
  hipLaunchKernelGGL(kperpoint, dim3(64),       dim3(256), 0, stream, pts, lbl, ws, acc);
  hipLaunchKernelGGL(kboundary, dim3(528, BB),  dim3(256), 0, stream, lbl, ws, acc);
  hipLaunchKernelGGL(klovasz,   dim3(64),       dim3(256), 0, stream, lbl, ws, acc);
  hipLaunchKernelGGL(kfinal,    dim3(1),        dim3(1),   0, stream, acc, out);
}

// Round 2
// 169.642 us; speedup vs baseline: 1.7709x; 1.7709x over previous
//
#include <hip/hip_runtime.h>

#define BB 4
#define NN 4096
#define DD 64
#define KK 16

// ws float offsets
#define OFF_EMB   0u          // B*N*D = 1048576 (fp32 normalized emb)
#define OFF_SIMT  1048576u    // B*K*N = 262144  (layout [b][k][n])
#define OFF_NRM2  1310720u    // B*N   = 16384
#define OFF_FCSUM 1327104u    // B*K*D = 4096
#define OFF_GCSUM 1331200u    // B*K*3 = 192
#define OFF_CNT   1331392u    // B*K   = 64
#define OFF_FC    1331456u    // 4096
#define OFF_CEN   1335552u    // 4096
#define OFF_GC    1339648u    // 192
#define OFF_FCN2  1339840u    // 64
#define OFF_FCN   1339904u    // 64
#define OFF_CEN2  1339968u    // 64
#define OFF_GC2   1340032u    // 64
#define OFF_ACC   1340096u    // 8 doubles (16 floats), 8B aligned
#define OFF_EMBH  1340112u    // bf16 normalized emb: B*N*D ushorts = 524288 float slots
#define WS_NEED_BYTES ((OFF_EMBH + 524288u) * 4u)
// acc: 0 var, 1 dist, 2 reg, 3 center, 4 boundary(raw upper-pair sum), 5 lovasz

typedef __attribute__((ext_vector_type(8))) short bf16x8;
typedef __attribute__((ext_vector_type(4))) float f32x4;

__device__ __forceinline__ ushort f2bf(float x){
  unsigned u = __float_as_uint(x);
  return (ushort)((u + 0x7FFFu + ((u >> 16) & 1u)) >> 16);
}

__device__ __forceinline__ float blockReduceSum(float v, float* sbuf){
  int t = threadIdx.x;
  #pragma unroll
  for (int off = 32; off > 0; off >>= 1) v += __shfl_xor(v, off, 64);
  if ((t & 63) == 0) sbuf[t >> 6] = v;
  __syncthreads();
  float s = 0.f;
  if (t == 0){
    int nw = blockDim.x >> 6;
    for (int i = 0; i < nw; i++) s += sbuf[i];
  }
  __syncthreads();
  return s;
}

__global__ void kinit(float* ws){
  int t = blockIdx.x * blockDim.x + threadIdx.x;
  int stride = blockDim.x * gridDim.x;
  for (int i = t; i < 4352; i += stride) ws[OFF_FCSUM + i] = 0.f;
  for (int i = t; i < 16;   i += stride) ws[OFF_ACC + i]   = 0.f;
}

// Normalize embeddings, per-instance sums. One wave handles 16 points; lane = dim.
__global__ void knormacc(const float* __restrict__ emb, const float* __restrict__ pts,
                         const int* __restrict__ lbl, float* __restrict__ ws, int useh){
  __shared__ float fcl[KK * DD];
  __shared__ float gcl[KK * 3];
  __shared__ float cntl[KK];
  int t = threadIdx.x;
  for (int i = t; i < KK * DD; i += 256) fcl[i] = 0.f;
  if (t < KK * 3) gcl[t] = 0.f;
  if (t < KK) cntl[t] = 0.f;
  __syncthreads();

  int lane = t & 63, w = t >> 6;
  int b = blockIdx.x >> 6;
  int local = blockIdx.x & 63;
  int base = local * 64 + w * 16;
  const float* E = emb + (size_t)b * NN * DD;
  float* EN = ws + OFF_EMB + (size_t)b * NN * DD;
  ushort* EH = (ushort*)(ws + OFF_EMBH) + (size_t)b * NN * DD;

  for (int i = 0; i < 16; i++){
    int n = base + i;
    float v = E[(size_t)n * DD + lane];
    float ss = v * v;
    #pragma unroll
    for (int off = 1; off < 64; off <<= 1) ss += __shfl_xor(ss, off, 64);
    float nrm = sqrtf(ss);
    float scale = 1.0f / fmaxf(nrm, 1e-12f);
    float vn = v * scale;
    EN[(size_t)n * DD + lane] = vn;
    if (useh) EH[(size_t)n * DD + lane] = f2bf(vn);
    if (lane == 0) ws[OFF_NRM2 + b * NN + n] = ss * scale * scale;
    int l = lbl[b * NN + n];
    if (l >= 1 && l <= KK){
      int k = l - 1;
      atomicAdd(&fcl[k * DD + lane], vn);
      if (lane < 3) atomicAdd(&gcl[k * 3 + lane], pts[((size_t)b * NN + n) * 3 + lane]);
      if (lane == 0) atomicAdd(&cntl[k], 1.0f);
    }
  }
  __syncthreads();
  for (int i = t; i < KK * DD; i += 256) atomicAdd(&ws[OFF_FCSUM + b * KK * DD + i], fcl[i]);
  if (t < KK * 3) atomicAdd(&ws[OFF_GCSUM + b * KK * 3 + t], gcl[t]);
  if (t < KK)     atomicAdd(&ws[OFF_CNT + b * KK + t], cntl[t]);
}

// Finalize centers, dist loss, reg loss. One block per batch.
__global__ void kcenters(float* __restrict__ ws, double* __restrict__ acc){
  __shared__ float cenS[KK * DD];
  __shared__ float cen2S[KK];
  __shared__ float red[16];
  int b = blockIdx.x, t = threadIdx.x;
  if (t < KK){
    int k = t;
    float c = ws[OFF_CNT + b * KK + k];
    float inv_c = 1.f / c;
    float n2 = 0.f;
    #pragma unroll
    for (int d = 0; d < DD; d++){
      float f = ws[OFF_FCSUM + (b * KK + k) * DD + d] * inv_c;
      ws[OFF_FC + (b * KK + k) * DD + d] = f;
      n2 += f * f;
    }
    float fn = sqrtf(n2);
    ws[OFF_FCN2 + b * KK + k] = n2;
    ws[OFF_FCN + b * KK + k] = fn;
    float inv = 1.f / fmaxf(fn, 1e-12f);
    float c2 = 0.f;
    #pragma unroll
    for (int d = 0; d < DD; d++){
      float ce = ws[OFF_FC + (b * KK + k) * DD + d] * inv;
      ws[OFF_CEN + (b * KK + k) * DD + d] = ce;
      cenS[k * DD + d] = ce;
      c2 += ce * ce;
    }
    ws[OFF_CEN2 + b * KK + k] = c2;
    cen2S[k] = c2;
    float g2 = 0.f;
    for (int j = 0; j < 3; j++){
      float g = ws[OFF_GCSUM + (b * KK + k) * 3 + j] * inv_c;
      ws[OFF_GC + (b * KK + k) * 3 + j] = g;
      g2 += g * g;
    }
    ws[OFF_GC2 + b * KK + k] = g2;
  }
  __syncthreads();
  int i = t >> 4, j = t & 15;
  float v = 0.f;
  if (i != j){
    float dot = 0.f;
    #pragma unroll
    for (int d = 0; d < DD; d++) dot += cenS[i * DD + d] * cenS[j * DD + d];
    float cd = sqrtf(fmaxf(cen2S[i] + cen2S[j] - 2.f * dot, 0.f));
    v = fmaxf(3.f - cd, 0.f);
  }
  float s = blockReduceSum(v, red);
  if (t == 0){
    atomicAdd(&acc[1], (double)(s / 240.f));
    float s2 = 0.f;
    for (int k = 0; k < KK; k++) s2 += cen2S[k];
    atomicAdd(&acc[2], (double)(sqrtf(s2) * 0.001f));
  }
}

// Per-point: sims for lovasz, var loss, center loss. Thread per point.
__global__ void kperpoint(const float* __restrict__ pts, const int* __restrict__ lbl,
                          float* __restrict__ ws, double* __restrict__ acc){
  __shared__ float4 fcl4[KK][16];
  __shared__ float fcnS[KK], fcn2S[KK], cen2S[KK], cntS[KK], invS[KK], gc2S[KK];
  __shared__ float gcS[KK][3];
  __shared__ float red[16];
  int t = threadIdx.x;
  int b = blockIdx.x >> 4;
  int n = (blockIdx.x & 15) * 256 + t;
  for (int i = t; i < KK * DD; i += 256) ((float*)fcl4)[i] = ws[OFF_FC + b * KK * DD + i];
  if (t < KK){
    float fn = ws[OFF_FCN + b * KK + t];
    fcnS[t] = fn;
    fcn2S[t] = ws[OFF_FCN2 + b * KK + t];
    cen2S[t] = ws[OFF_CEN2 + b * KK + t];
    cntS[t] = ws[OFF_CNT + b * KK + t];
    invS[t] = 1.f / fmaxf(fn, 1e-12f);
    gc2S[t] = ws[OFF_GC2 + b * KK + t];
    gcS[t][0] = ws[OFF_GC + (b * KK + t) * 3 + 0];
    gcS[t][1] = ws[OFF_GC + (b * KK + t) * 3 + 1];
    gcS[t][2] = ws[OFF_GC + (b * KK + t) * 3 + 2];
  }
  __syncthreads();

  const float* EN = ws + OFF_EMB + ((size_t)(b * NN + n)) * DD;
  float4 v[16];
  #pragma unroll
  for (int i = 0; i < 16; i++) v[i] = *(const float4*)&EN[i * 4];
  float nrm2 = ws[OFF_NRM2 + b * NN + n];
  float nrm = sqrtf(nrm2);
  int l = lbl[b * NN + n];
  float p0 = pts[((size_t)b * NN + n) * 3 + 0];
  float p1 = pts[((size_t)b * NN + n) * 3 + 1];
  float p2 = pts[((size_t)b * NN + n) * 3 + 2];
  float p2sum = p0 * p0 + p1 * p1 + p2 * p2;
  float varA = 0.f, cenA = 0.f;

  for (int k = 0; k < KK; k++){
    float dot = 0.f;
    #pragma unroll
    for (int i = 0; i < 16; i++){
      float4 f = fcl4[k][i];
      dot += v[i].x * f.x + v[i].y * f.y + v[i].z * f.z + v[i].w * f.w;
    }
    float sim = dot / (fmaxf(nrm, 1e-8f) * fmaxf(fcnS[k], 1e-8f));
    ws[OFF_SIMT + (size_t)(b * KK + k) * NN + n] = sim;
    if (l == k + 1){
      float dotc = dot * invS[k];
      float dnc = sqrtf(fmaxf(nrm2 + cen2S[k] - 2.f * dotc, 0.f));
      varA += fmaxf(dnc - 0.5f, 0.f) / cntS[k];
      float fd = sqrtf(fmaxf(nrm2 + fcn2S[k] - 2.f * dot, 0.f));
      float gd2 = p2sum + gc2S[k] - 2.f * (p0 * gcS[k][0] + p1 * gcS[k][1] + p2 * gcS[k][2]);
      float sd = sqrtf(fmaxf(gd2, 0.f));
      cenA += sd * fd / cntS[k];
    }
  }
  float vs = blockReduceSum(varA, red);
  if (t == 0) atomicAdd(&acc[0], (double)vs);
  float cs = blockReduceSum(cenA, red);
  if (t == 0) atomicAdd(&acc[3], (double)cs);
}

#define TS 128
#define LDST 68
// Fallback fp32 boundary (used only if ws too small for bf16 buffer).
__global__ __launch_bounds__(256, 2) void kboundary(const int* __restrict__ lbl,
                                                    float* __restrict__ ws,
                                                    double* __restrict__ acc){
  __shared__ float As[TS * LDST];
  __shared__ float Bs[TS * LDST];
  __shared__ int lA[TS], lB[TS];
  __shared__ float nA[TS], nB[TS];
  __shared__ float red[16];
  int t = threadIdx.x;
  int b = blockIdx.y;
  int rem = blockIdx.x, ti = 0;
  while (rem >= 32 - ti){ rem -= 32 - ti; ti++; }
  int tj = ti + rem;
  const float* E = ws + OFF_EMB + (size_t)b * NN * DD;

  #pragma unroll
  for (int q = 0; q < 8; q++){
    int l4 = t + q * 256;
    int row = l4 >> 4, c4 = l4 & 15;
    float4 va = *(const float4*)&E[(size_t)(ti * TS + row) * DD + c4 * 4];
    *(float4*)&As[row * LDST + c4 * 4] = va;
    float4 vb = *(const float4*)&E[(size_t)(tj * TS + row) * DD + c4 * 4];
    *(float4*)&Bs[row * LDST + c4 * 4] = vb;
  }
  if (t < TS){
    lA[t] = lbl[b * NN + ti * TS + t];
    nA[t] = ws[OFF_NRM2 + b * NN + ti * TS + t];
  } else if (t < 2 * TS){
    int u = t - TS;
    lB[u] = lbl[b * NN + tj * TS + u];
    nB[u] = ws[OFF_NRM2 + b * NN + tj * TS + u];
  }
  __syncthreads();

  int tx = t & 15, ty = t >> 4;
  float accr[8][8];
  #pragma unroll
  for (int r = 0; r < 8; r++)
    #pragma unroll
    for (int c = 0; c < 8; c++) accr[r][c] = 0.f;

  for (int k = 0; k < DD; k += 4){
    float4 a4[8], b4[8];
    #pragma unroll
    for (int r = 0; r < 8; r++) a4[r] = *(const float4*)&As[(ty + 16 * r) * LDST + k];
    #pragma unroll
    for (int c = 0; c < 8; c++) b4[c] = *(const float4*)&Bs[(tx + 16 * c) * LDST + k];
    #pragma unroll
    for (int r = 0; r < 8; r++)
      #pragma unroll
      for (int c = 0; c < 8; c++)
        accr[r][c] += a4[r].x * b4[c].x + a4[r].y * b4[c].y
                    + a4[r].z * b4[c].z + a4[r].w * b4[c].w;
  }

  float sum = 0.f;
  #pragma unroll
  for (int r = 0; r < 8; r++){
    int ia = ty + 16 * r;
    int gi = ti * TS + ia;
    #pragma unroll
    for (int c = 0; c < 8; c++){
      int ib = tx + 16 * c;
      int gj = tj * TS + ib;
      if (gi < gj){
        float d2 = nA[ia] + nB[ib] - 2.f * accr[r][c];
        float d = sqrtf(fmaxf(d2, 0.f));
        float f = (lA[ia] == lB[ib]) ? 1.5f : fmaxf(1.5f - d, 0.f);
        sum += f;
      }
    }
  }
  float s = blockReduceSum(sum, red);
  if (t == 0) atomicAdd(&acc[4], (double)s);
}

// bf16 MFMA boundary: gram fragments straight from global (L2-resident, 512KB/batch).
// Gram symmetry => A-frag and B-frag load patterns are identical:
// lane reads 8 contiguous k at row (lane&15), k-chunk (lane>>4)*8.
__global__ __launch_bounds__(256) void kboundary_mfma(const int* __restrict__ lbl,
                                                      const ushort* __restrict__ EHg,
                                                      float* __restrict__ ws,
                                                      double* __restrict__ acc){
  __shared__ float nA[TS], nB[TS];
  __shared__ int lA[TS], lB[TS];
  __shared__ float red[16];
  int t = threadIdx.x;
  int b = blockIdx.y;
  int rem = blockIdx.x, ti = 0;
  while (rem >= 32 - ti){ rem -= 32 - ti; ti++; }
  int tj = ti + rem;
  if (t < TS){
    lA[t] = lbl[b * NN + ti * TS + t];
    nA[t] = ws[OFF_NRM2 + b * NN + ti * TS + t];
  } else if (t < 2 * TS){
    int u = t - TS;
    lB[u] = lbl[b * NN + tj * TS + u];
    nB[u] = ws[OFF_NRM2 + b * NN + tj * TS + u];
  }
  __syncthreads();

  int lane = t & 63, w = t >> 6;
  const ushort* E = EHg + (size_t)b * NN * DD;
  int lm = lane & 15, lk = (lane >> 4) * 8;

  f32x4 accf[2][8];
  #pragma unroll
  for (int rb = 0; rb < 2; rb++)
    #pragma unroll
    for (int cb = 0; cb < 8; cb++) accf[rb][cb] = (f32x4){0.f, 0.f, 0.f, 0.f};

  #pragma unroll
  for (int kh = 0; kh < 2; kh++){
    bf16x8 a0 = *(const bf16x8*)&E[(size_t)(ti * TS + w * 32 + lm) * DD + kh * 32 + lk];
    bf16x8 a1 = *(const bf16x8*)&E[(size_t)(ti * TS + w * 32 + 16 + lm) * DD + kh * 32 + lk];
    #pragma unroll
    for (int cb = 0; cb < 8; cb++){
      bf16x8 bb = *(const bf16x8*)&E[(size_t)(tj * TS + cb * 16 + lm) * DD + kh * 32 + lk];
      accf[0][cb] = __builtin_amdgcn_mfma_f32_16x16x32_bf16(a0, bb, accf[0][cb], 0, 0, 0);
      accf[1][cb] = __builtin_amdgcn_mfma_f32_16x16x32_bf16(a1, bb, accf[1][cb], 0, 0, 0);
    }
  }

  float sum = 0.f;
  int rif = (lane >> 4) * 4;
  #pragma unroll
  for (int rb = 0; rb < 2; rb++){
    #pragma unroll
    for (int cb = 0; cb < 8; cb++){
      #pragma unroll
      for (int r = 0; r < 4; r++){
        int ia = w * 32 + rb * 16 + rif + r;
        int ib = cb * 16 + lm;
        int gi = ti * TS + ia, gj = tj * TS + ib;
        if (gi < gj){
          float d2 = nA[ia] + nB[ib] - 2.f * accf[rb][cb][r];
          float d = sqrtf(fmaxf(d2, 0.f));
          sum += (lA[ia] == lB[ib]) ? 1.5f : fmaxf(1.5f - d, 0.f);
        }
      }
    }
  }
  float s = blockReduceSum(sum, red);
  if (t == 0) atomicAdd(&acc[4], (double)s);
}

// Lovasz: one 1024-thread block per (b,k). Bitonic sort of u64 keys in LDS.
__global__ __launch_bounds__(1024) void klovasz(const int* __restrict__ lbl,
                                                float* __restrict__ ws,
                                                double* __restrict__ acc){
  __shared__ unsigned long long key[NN];   // 32 KB
  __shared__ unsigned mbits[NN / 32];      // 512 B
  __shared__ int psum[1024];
  __shared__ float red[16];
  int t = threadIdx.x;
  int bk = blockIdx.x;
  int b = bk >> 4, k = bk & 15;
  const float* sim = ws + OFF_SIMT + (size_t)bk * NN;

  #pragma unroll
  for (int j = 0; j < 4; j++){
    int n = t + j * 1024;
    unsigned u = __float_as_uint(sim[n]);
    unsigned asc = (u & 0x80000000u) ? ~u : (u | 0x80000000u);
    key[n] = ((unsigned long long)(~asc) << 32) | (unsigned)n;
  }
  if (t < NN / 32){
    unsigned m = 0;
    #pragma unroll
    for (int q = 0; q < 32; q++)
      if (lbl[b * NN + t * 32 + q] == k + 1) m |= (1u << q);
    mbits[t] = m;
  }
  __syncthreads();

  for (int size = 2; size <= NN; size <<= 1){
    for (int stride = size >> 1; stride > 0; stride >>= 1){
      #pragma unroll
      for (int j = 0; j < 4; j++){
        int i = t + j * 1024;
        int p = i ^ stride;
        if (p > i){
          unsigned long long a = key[i], c = key[p];
          bool sw = ((i & size) == 0) ? (a > c) : (a < c);
          if (sw){ key[i] = c; key[p] = a; }
        }
      }
      __syncthreads();
    }
  }

  float cntk = ws[OFF_CNT + b * KK + k];
  int c0 = t * 4;
  int local = 0;
  int mloc[4];
  #pragma unroll
  for (int q = 0; q < 4; q++){
    int idx = (int)(unsigned)key[c0 + q];
    int m = (mbits[idx >> 5] >> (idx & 31)) & 1;
    mloc[q] = m;
    local += m;
  }
  psum[t] = local;
  __syncthreads();
  for (int off = 1; off < 1024; off <<= 1){
    int add = (t >= off) ? psum[t - off] : 0;
    __syncthreads();
    psum[t] += add;
    __syncthreads();
  }
  int base = psum[t] - local;

  float csum = (float)base;
  float jprev;
  if (c0 == 0) jprev = 0.f;
  else {
    float inter = cntk - (float)base;
    float uni = cntk + (float)c0 - (float)base;
    jprev = 1.f - inter / uni;
  }
  float lsum = 0.f;
  #pragma unroll
  for (int q = 0; q < 4; q++){
    int i = c0 + q;
    unsigned long long kk = key[i];
    unsigned asc = ~((unsigned)(kk >> 32));
    unsigned u = (asc & 0x80000000u) ? (asc ^ 0x80000000u) : ~asc;
    float ss = __uint_as_float(u);
    csum += (float)mloc[q];
    float inter = cntk - csum;
    float uni = cntk + (float)(i + 1) - csum;
    float jac = 1.f - inter / uni;
    lsum += fmaxf(ss, 0.f) * (jac - jprev);
    jprev = jac;
  }
  float tot = blockReduceSum(lsum, red);
  if (t == 0) atomicAdd(&acc[5], (double)tot);
}

__global__ void kfinal(const double* __restrict__ acc, float* __restrict__ out){
  if (threadIdx.x == 0 && blockIdx.x == 0){
    double var_l  = acc[0] / (4.0 + 1e-6);
    double dist_l = acc[1] / (4.0 + 1e-6);
    double reg_l  = acc[2] / (4.0 + 1e-6);
    double cen_l  = acc[3] / 4.0;
    double bnd_l  = (2.0 * acc[4] + 1.5 * (double)NN * BB) / ((double)NN * NN * BB);
    double lov_l  = acc[5] / 4.0;
    double total = 0.1 * (var_l + dist_l + reg_l) + 0.1 * cen_l + 0.05 * bnd_l + 0.01 * lov_l;
    out[0] = (float)total; out[1] = (float)var_l; out[2] = (float)dist_l;
    out[3] = (float)reg_l; out[4] = (float)cen_l; out[5] = (float)bnd_l;
    out[6] = (float)lov_l;
  }
}

extern "C" void kernel_launch(void* const* d_in, const int* in_sizes, int n_in,
                              void* d_out, int out_size, void* d_ws, size_t ws_size,
                              hipStream_t stream){
  const float* pts = (const float*)d_in[0];
  const float* emb = (const float*)d_in[1];
  const int* lbl   = (const int*)d_in[2];
  float* out = (float*)d_out;
  float* ws = (float*)d_ws;
  double* acc = (double*)(ws + OFF_ACC);
  int useh = (ws_size >= (size_t)WS_NEED_BYTES) ? 1 : 0;

  hipLaunchKernelGGL(kinit,     dim3(4),   dim3(256), 0, stream, ws);
  hipLaunchKernelGGL(knormacc,  dim3(256), dim3(256), 0, stream, emb, pts, lbl, ws, useh);
  hipLaunchKernelGGL(kcenters,  dim3(BB),  dim3(256), 0, stream, ws, acc);
  hipLaunchKernelGGL(kperpoint, dim3(64),  dim3(256), 0, stream, pts, lbl, ws, acc);
  if (useh){
    hipLaunchKernelGGL(kboundary_mfma, dim3(528, BB), dim3(256), 0, stream,
                       lbl, (const ushort*)(ws + OFF_EMBH), ws, acc);
  } else {
    hipLaunchKernelGGL(kboundary, dim3(528, BB), dim3(256), 0, stream, lbl, ws, acc);
  }
  hipLaunchKernelGGL(klovasz,   dim3(64),  dim3(1024), 0, stream, lbl, ws, acc);
  hipLaunchKernelGGL(kfinal,    dim3(1),   dim3(1),    0, stream, acc, out);
}

// Round 3
// 110.684 us; speedup vs baseline: 2.7141x; 1.5327x over previous
//
#include <hip/hip_runtime.h>

#define BB 4
#define NN 4096
#define DD 64
#define KK 16

// ws float offsets
#define OFF_EMB   0u          // B*N*D = 1048576 (fp32 normalized emb)
#define OFF_SIMT  1048576u    // B*K*N = 262144  (layout [b][k][n])
#define OFF_NRM2  1310720u    // B*N   = 16384
#define OFF_FCSUM 1327104u    // B*K*D = 4096
#define OFF_GCSUM 1331200u    // B*K*3 = 192
#define OFF_CNT   1331392u    // B*K   = 64
#define OFF_FC    1331456u    // 4096
#define OFF_CEN   1335552u    // 4096
#define OFF_GC    1339648u    // 192
#define OFF_FCN2  1339840u    // 64
#define OFF_FCN   1339904u    // 64
#define OFF_CEN2  1339968u    // 64
#define OFF_GC2   1340032u    // 64
#define OFF_ACC   1340096u    // 8 doubles (16 floats), 8B aligned
#define OFF_EMBH  1340112u    // bf16 normalized emb: B*N*D ushorts = 524288 float slots
// acc: 0 var, 1 dist, 2 reg, 3 center, 4 boundary(raw upper-pair sum), 5 lovasz

typedef __attribute__((ext_vector_type(8))) short bf16x8;
typedef __attribute__((ext_vector_type(4))) float f32x4;
typedef unsigned long long ull;

__device__ __forceinline__ ushort f2bf(float x){
  unsigned u = __float_as_uint(x);
  return (ushort)((u + 0x7FFFu + ((u >> 16) & 1u)) >> 16);
}

__device__ __forceinline__ float blockReduceSum(float v, float* sbuf){
  int t = threadIdx.x;
  #pragma unroll
  for (int off = 32; off > 0; off >>= 1) v += __shfl_xor(v, off, 64);
  if ((t & 63) == 0) sbuf[t >> 6] = v;
  __syncthreads();
  float s = 0.f;
  if (t == 0){
    int nw = blockDim.x >> 6;
    for (int i = 0; i < nw; i++) s += sbuf[i];
  }
  __syncthreads();
  return s;
}

// Normalize embeddings, per-instance sums. One wave handles 16 points; lane = dim.
__global__ void knormacc(const float* __restrict__ emb, const float* __restrict__ pts,
                         const int* __restrict__ lbl, float* __restrict__ ws){
  __shared__ float fcl[KK * DD];
  __shared__ float gcl[KK * 3];
  __shared__ float cntl[KK];
  int t = threadIdx.x;
  for (int i = t; i < KK * DD; i += 256) fcl[i] = 0.f;
  if (t < KK * 3) gcl[t] = 0.f;
  if (t < KK) cntl[t] = 0.f;
  __syncthreads();

  int lane = t & 63, w = t >> 6;
  int b = blockIdx.x >> 6;
  int local = blockIdx.x & 63;
  int base = local * 64 + w * 16;
  const float* E = emb + (size_t)b * NN * DD;
  float* EN = ws + OFF_EMB + (size_t)b * NN * DD;
  ushort* EH = (ushort*)(ws + OFF_EMBH) + (size_t)b * NN * DD;

  for (int i = 0; i < 16; i++){
    int n = base + i;
    float v = E[(size_t)n * DD + lane];
    float ss = v * v;
    #pragma unroll
    for (int off = 1; off < 64; off <<= 1) ss += __shfl_xor(ss, off, 64);
    float nrm = sqrtf(ss);
    float scale = 1.0f / fmaxf(nrm, 1e-12f);
    float vn = v * scale;
    EN[(size_t)n * DD + lane] = vn;
    EH[(size_t)n * DD + lane] = f2bf(vn);
    if (lane == 0) ws[OFF_NRM2 + b * NN + n] = ss * scale * scale;
    int l = lbl[b * NN + n];
    if (l >= 1 && l <= KK){
      int k = l - 1;
      atomicAdd(&fcl[k * DD + lane], vn);
      if (lane < 3) atomicAdd(&gcl[k * 3 + lane], pts[((size_t)b * NN + n) * 3 + lane]);
      if (lane == 0) atomicAdd(&cntl[k], 1.0f);
    }
  }
  __syncthreads();
  for (int i = t; i < KK * DD; i += 256) atomicAdd(&ws[OFF_FCSUM + b * KK * DD + i], fcl[i]);
  if (t < KK * 3) atomicAdd(&ws[OFF_GCSUM + b * KK * 3 + t], gcl[t]);
  if (t < KK)     atomicAdd(&ws[OFF_CNT + b * KK + t], cntl[t]);
}

// Finalize centers, dist loss, reg loss. One block per batch.
__global__ void kcenters(float* __restrict__ ws, double* __restrict__ acc){
  __shared__ float cenS[KK * DD];
  __shared__ float cen2S[KK];
  __shared__ float red[16];
  int b = blockIdx.x, t = threadIdx.x;
  if (t < KK){
    int k = t;
    float c = ws[OFF_CNT + b * KK + k];
    float inv_c = 1.f / c;
    float n2 = 0.f;
    #pragma unroll
    for (int d = 0; d < DD; d++){
      float f = ws[OFF_FCSUM + (b * KK + k) * DD + d] * inv_c;
      ws[OFF_FC + (b * KK + k) * DD + d] = f;
      n2 += f * f;
    }
    float fn = sqrtf(n2);
    ws[OFF_FCN2 + b * KK + k] = n2;
    ws[OFF_FCN + b * KK + k] = fn;
    float inv = 1.f / fmaxf(fn, 1e-12f);
    float c2 = 0.f;
    #pragma unroll
    for (int d = 0; d < DD; d++){
      float ce = ws[OFF_FC + (b * KK + k) * DD + d] * inv;
      cenS[k * DD + d] = ce;
      c2 += ce * ce;
    }
    ws[OFF_CEN2 + b * KK + k] = c2;
    cen2S[k] = c2;
    float g2 = 0.f;
    for (int j = 0; j < 3; j++){
      float g = ws[OFF_GCSUM + (b * KK + k) * 3 + j] * inv_c;
      ws[OFF_GC + (b * KK + k) * 3 + j] = g;
      g2 += g * g;
    }
    ws[OFF_GC2 + b * KK + k] = g2;
  }
  __syncthreads();
  int i = t >> 4, j = t & 15;
  float v = 0.f;
  if (i != j){
    float dot = 0.f;
    #pragma unroll
    for (int d = 0; d < DD; d++) dot += cenS[i * DD + d] * cenS[j * DD + d];
    float cd = sqrtf(fmaxf(cen2S[i] + cen2S[j] - 2.f * dot, 0.f));
    v = fmaxf(3.f - cd, 0.f);
  }
  float s = blockReduceSum(v, red);
  if (t == 0){
    atomicAdd(&acc[1], (double)(s / 240.f));
    float s2 = 0.f;
    for (int k = 0; k < KK; k++) s2 += cen2S[k];
    atomicAdd(&acc[2], (double)(sqrtf(s2) * 0.001f));
  }
}

// Per-point: sims for lovasz, var loss, center loss. Thread per point. 128 thr/block.
__global__ void kperpoint(const float* __restrict__ pts, const int* __restrict__ lbl,
                          float* __restrict__ ws, double* __restrict__ acc){
  __shared__ float4 fcl4[KK][16];
  __shared__ float fcnS[KK], fcn2S[KK], cen2S[KK], cntS[KK], invS[KK], gc2S[KK];
  __shared__ float gcS[KK][3];
  __shared__ float red[16];
  int t = threadIdx.x;
  int g = blockIdx.x * 128 + t;
  int b = g >> 12;
  int n = g & (NN - 1);
  for (int i = t; i < KK * DD; i += 128) ((float*)fcl4)[i] = ws[OFF_FC + b * KK * DD + i];
  if (t < KK){
    float fn = ws[OFF_FCN + b * KK + t];
    fcnS[t] = fn;
    fcn2S[t] = ws[OFF_FCN2 + b * KK + t];
    cen2S[t] = ws[OFF_CEN2 + b * KK + t];
    cntS[t] = ws[OFF_CNT + b * KK + t];
    invS[t] = 1.f / fmaxf(fn, 1e-12f);
    gc2S[t] = ws[OFF_GC2 + b * KK + t];
    gcS[t][0] = ws[OFF_GC + (b * KK + t) * 3 + 0];
    gcS[t][1] = ws[OFF_GC + (b * KK + t) * 3 + 1];
    gcS[t][2] = ws[OFF_GC + (b * KK + t) * 3 + 2];
  }
  __syncthreads();

  const float* EN = ws + OFF_EMB + ((size_t)(b * NN + n)) * DD;
  float4 v[16];
  #pragma unroll
  for (int i = 0; i < 16; i++) v[i] = *(const float4*)&EN[i * 4];
  float nrm2 = ws[OFF_NRM2 + b * NN + n];
  float nrm = sqrtf(nrm2);
  int l = lbl[b * NN + n];
  float p0 = pts[((size_t)b * NN + n) * 3 + 0];
  float p1 = pts[((size_t)b * NN + n) * 3 + 1];
  float p2 = pts[((size_t)b * NN + n) * 3 + 2];
  float p2sum = p0 * p0 + p1 * p1 + p2 * p2;
  float varA = 0.f, cenA = 0.f;

  for (int k = 0; k < KK; k++){
    float dot = 0.f;
    #pragma unroll
    for (int i = 0; i < 16; i++){
      float4 f = fcl4[k][i];
      dot += v[i].x * f.x + v[i].y * f.y + v[i].z * f.z + v[i].w * f.w;
    }
    float sim = dot / (fmaxf(nrm, 1e-8f) * fmaxf(fcnS[k], 1e-8f));
    ws[OFF_SIMT + (size_t)(b * KK + k) * NN + n] = sim;
    if (l == k + 1){
      float dotc = dot * invS[k];
      float dnc = sqrtf(fmaxf(nrm2 + cen2S[k] - 2.f * dotc, 0.f));
      varA += fmaxf(dnc - 0.5f, 0.f) / cntS[k];
      float fd = sqrtf(fmaxf(nrm2 + fcn2S[k] - 2.f * dot, 0.f));
      float gd2 = p2sum + gc2S[k] - 2.f * (p0 * gcS[k][0] + p1 * gcS[k][1] + p2 * gcS[k][2]);
      float sd = sqrtf(fmaxf(gd2, 0.f));
      cenA += sd * fd / cntS[k];
    }
  }
  float vs = blockReduceSum(varA, red);
  if (t == 0) atomicAdd(&acc[0], (double)vs);
  float cs = blockReduceSum(cenA, red);
  if (t == 0) atomicAdd(&acc[3], (double)cs);
}

// Fused: blocks 0..63 = lovasz (one per (b,k)); blocks 64.. = boundary 128x128 tiles.
__global__ __launch_bounds__(256, 4) void kfused(const int* __restrict__ lbl,
                                                 const ushort* __restrict__ EHg,
                                                 float* __restrict__ ws,
                                                 double* __restrict__ accd){
  __shared__ union SMem {
    struct { ull key[NN]; int wt[64]; float red[16]; } lv;
    struct { float red[16]; } bd;
  } sm;
  int t = threadIdx.x;

  if (blockIdx.x < 64){
    // ================= LOVASZ =================
    int bk = blockIdx.x;
    int b = bk >> 4, k = bk & 15;
    const float* sim = ws + OFF_SIMT + (size_t)bk * NN;
    int lane = t & 63, wv = t >> 6;
    ull key[16];
    #pragma unroll
    for (int s2 = 0; s2 < 16; s2++){
      int p = s2 * 256 + t;
      unsigned u = __float_as_uint(sim[p]);
      unsigned a = (u & 0x80000000u) ? ~u : (u | 0x80000000u);
      key[s2] = ((ull)(~a) << 32) | (unsigned)p;
    }
    // bitonic: position p = s2*256 + t; strides>=256 in-thread, 64/128 via LDS, <=32 via shfl
    #pragma unroll
    for (int ls = 1; ls <= 12; ls++){
      const int S = 1 << ls;
      #pragma unroll
      for (int lg = ls - 1; lg >= 8; lg--){
        const int c = 1 << (lg - 8);
        #pragma unroll
        for (int lo = 0; lo < 16; lo++){
          if ((lo & c) == 0){
            const int hi = lo | c;
            ull A = key[lo], B2 = key[hi];
            bool asc2 = ((lo << 8) & S) == 0;
            ull mn = (A < B2) ? A : B2;
            ull mx = (A < B2) ? B2 : A;
            key[lo] = asc2 ? mn : mx;
            key[hi] = asc2 ? mx : mn;
          }
        }
      }
      #pragma unroll
      for (int lg = (ls - 1 < 7 ? ls - 1 : 7); lg >= 6; lg--){
        const int sig = 1 << lg;
        __syncthreads();
        #pragma unroll
        for (int s2 = 0; s2 < 16; s2++) sm.lv.key[s2 * 256 + t] = key[s2];
        __syncthreads();
        #pragma unroll
        for (int s2 = 0; s2 < 16; s2++){
          ull part = sm.lv.key[s2 * 256 + (t ^ sig)];
          int p = s2 * 256 + t;
          bool asc2 = (p & S) == 0;
          bool low = (t & sig) == 0;
          ull mn = (key[s2] < part) ? key[s2] : part;
          ull mx = (key[s2] < part) ? part : key[s2];
          key[s2] = (asc2 == low) ? mn : mx;
        }
      }
      #pragma unroll
      for (int lg = (ls - 1 < 5 ? ls - 1 : 5); lg >= 0; lg--){
        const int sig = 1 << lg;
        #pragma unroll
        for (int s2 = 0; s2 < 16; s2++){
          unsigned klo = (unsigned)key[s2];
          unsigned khi = (unsigned)(key[s2] >> 32);
          unsigned plo = __shfl_xor(klo, sig, 64);
          unsigned phi = __shfl_xor(khi, sig, 64);
          ull part = ((ull)phi << 32) | (ull)plo;
          int p = s2 * 256 + t;
          bool asc2 = (p & S) == 0;
          bool low = (t & sig) == 0;
          ull mn = (key[s2] < part) ? key[s2] : part;
          ull mx = (key[s2] < part) ? part : key[s2];
          key[s2] = (asc2 == low) ? mn : mx;
        }
      }
    }
    // epilogue: masks via ballot, exact integer prefix, jaccard
    float cntk = ws[OFF_CNT + b * KK + k];
    int m[16], pw[16];
    __syncthreads();
    #pragma unroll
    for (int s2 = 0; s2 < 16; s2++){
      int idx = (int)(key[s2] & 0xFFFFFFFFull);
      m[s2] = (lbl[b * NN + idx] == k + 1) ? 1 : 0;
      ull bl = __ballot(m[s2]);
      pw[s2] = (int)__popcll(bl & ((1ull << lane) - 1ull));
      if (lane == 0) sm.lv.wt[s2 * 4 + wv] = (int)__popcll(bl);
    }
    __syncthreads();
    int baseex[16];
    { int run = 0;
      #pragma unroll
      for (int s2 = 0; s2 < 16; s2++){
        int wb = 0, st = 0;
        #pragma unroll
        for (int w2 = 0; w2 < 4; w2++){
          int vv = sm.lv.wt[s2 * 4 + w2];
          st += vv; if (w2 < wv) wb += vv;
        }
        baseex[s2] = run + wb;
        run += st;
      }
    }
    float lsum = 0.f;
    #pragma unroll
    for (int s2 = 0; s2 < 16; s2++){
      int p = s2 * 256 + t;
      int base = baseex[s2] + pw[s2];
      float jprev;
      if (p == 0) jprev = 0.f;
      else {
        float inter = cntk - (float)base;
        float uni = cntk + (float)p - (float)base;
        jprev = 1.f - inter / uni;
      }
      float csum = (float)(base + m[s2]);
      float inter = cntk - csum;
      float uni = cntk + (float)(p + 1) - csum;
      float jac = 1.f - inter / uni;
      unsigned a2 = ~((unsigned)(key[s2] >> 32));
      unsigned u2 = (a2 & 0x80000000u) ? (a2 ^ 0x80000000u) : ~a2;
      float ss = __uint_as_float(u2);
      lsum += fmaxf(ss, 0.f) * (jac - jprev);
    }
    float tot = blockReduceSum(lsum, sm.lv.red);
    if (t == 0) atomicAdd(&accd[5], (double)tot);
  } else {
    // ================= BOUNDARY =================
    int q = blockIdx.x - 64;
    int b = q / 528;
    int rem = q - b * 528;
    int ti = 0;
    while (rem >= 32 - ti){ rem -= 32 - ti; ti++; }
    int tj = ti + rem;
    bool diag = (ti == tj);
    int lane = t & 63, w = t >> 6;
    int lm = lane & 15;
    int rif = (lane >> 4) * 4;
    int lk = (lane >> 4) * 8;
    const ushort* E = EHg + (size_t)b * NN * DD;
    const float* NR = ws + OFF_NRM2 + b * NN;
    const int* LB = lbl + b * NN;

    bf16x8 a[2][2];
    #pragma unroll
    for (int rb = 0; rb < 2; rb++)
      #pragma unroll
      for (int kh = 0; kh < 2; kh++)
        a[rb][kh] = *(const bf16x8*)&E[(size_t)(ti * 128 + w * 32 + rb * 16 + lm) * DD + kh * 32 + lk];

    float nAr[8]; int lAr[8];
    #pragma unroll
    for (int rb = 0; rb < 2; rb++)
      #pragma unroll
      for (int r = 0; r < 4; r++){
        int gi = ti * 128 + w * 32 + rb * 16 + rif + r;
        nAr[rb * 4 + r] = NR[gi];
        lAr[rb * 4 + r] = LB[gi];
      }

    float sum = 0.f;
    #pragma unroll
    for (int pass = 0; pass < 2; pass++){
      float nBr[4]; int lBr[4];
      #pragma unroll
      for (int cb = 0; cb < 4; cb++){
        int gj = tj * 128 + (pass * 4 + cb) * 16 + lm;
        nBr[cb] = NR[gj];
        lBr[cb] = LB[gj];
      }
      f32x4 ac[2][4];
      #pragma unroll
      for (int rb = 0; rb < 2; rb++)
        #pragma unroll
        for (int cb = 0; cb < 4; cb++) ac[rb][cb] = (f32x4){0.f, 0.f, 0.f, 0.f};
      #pragma unroll
      for (int cb = 0; cb < 4; cb++){
        #pragma unroll
        for (int kh = 0; kh < 2; kh++){
          bf16x8 bb = *(const bf16x8*)&E[(size_t)(tj * 128 + (pass * 4 + cb) * 16 + lm) * DD + kh * 32 + lk];
          ac[0][cb] = __builtin_amdgcn_mfma_f32_16x16x32_bf16(a[0][kh], bb, ac[0][cb], 0, 0, 0);
          ac[1][cb] = __builtin_amdgcn_mfma_f32_16x16x32_bf16(a[1][kh], bb, ac[1][cb], 0, 0, 0);
        }
      }
      if (diag){
        #pragma unroll
        for (int rb = 0; rb < 2; rb++)
          #pragma unroll
          for (int cb = 0; cb < 4; cb++)
            #pragma unroll
            for (int r = 0; r < 4; r++){
              float d2 = nAr[rb * 4 + r] + nBr[cb] - 2.f * ac[rb][cb][r];
              float d = sqrtf(fmaxf(d2, 0.f));
              float f = (lAr[rb * 4 + r] == lBr[cb]) ? 1.5f : fmaxf(1.5f - d, 0.f);
              int gi = w * 32 + rb * 16 + rif + r;
              int gj = (pass * 4 + cb) * 16 + lm;
              if (gi < gj) sum += f;
            }
      } else {
        #pragma unroll
        for (int rb = 0; rb < 2; rb++)
          #pragma unroll
          for (int cb = 0; cb < 4; cb++)
            #pragma unroll
            for (int r = 0; r < 4; r++){
              float d2 = nAr[rb * 4 + r] + nBr[cb] - 2.f * ac[rb][cb][r];
              float d = sqrtf(fmaxf(d2, 0.f));
              float f = (lAr[rb * 4 + r] == lBr[cb]) ? 1.5f : fmaxf(1.5f - d, 0.f);
              sum += f;
            }
      }
    }
    float s = blockReduceSum(sum, sm.bd.red);
    if (t == 0) atomicAdd(&accd[4], (double)s);
  }
}

__global__ void kfinal(const double* __restrict__ acc, float* __restrict__ out){
  if (threadIdx.x == 0 && blockIdx.x == 0){
    double var_l  = acc[0] / (4.0 + 1e-6);
    double dist_l = acc[1] / (4.0 + 1e-6);
    double reg_l  = acc[2] / (4.0 + 1e-6);
    double cen_l  = acc[3] / 4.0;
    double bnd_l  = (2.0 * acc[4] + 1.5 * (double)NN * BB) / ((double)NN * NN * BB);
    double lov_l  = acc[5] / 4.0;
    double total = 0.1 * (var_l + dist_l + reg_l) + 0.1 * cen_l + 0.05 * bnd_l + 0.01 * lov_l;
    out[0] = (float)total; out[1] = (float)var_l; out[2] = (float)dist_l;
    out[3] = (float)reg_l; out[4] = (float)cen_l; out[5] = (float)bnd_l;
    out[6] = (float)lov_l;
  }
}

extern "C" void kernel_launch(void* const* d_in, const int* in_sizes, int n_in,
                              void* d_out, int out_size, void* d_ws, size_t ws_size,
                              hipStream_t stream){
  const float* pts = (const float*)d_in[0];
  const float* emb = (const float*)d_in[1];
  const int* lbl   = (const int*)d_in[2];
  float* out = (float*)d_out;
  float* ws = (float*)d_ws;
  double* acc = (double*)(ws + OFF_ACC);

  hipMemsetAsync(ws + OFF_FCSUM, 0, 4352 * sizeof(float), stream);
  hipMemsetAsync(ws + OFF_ACC, 0, 16 * sizeof(float), stream);
  hipLaunchKernelGGL(knormacc,  dim3(256), dim3(256), 0, stream, emb, pts, lbl, ws);
  hipLaunchKernelGGL(kcenters,  dim3(BB),  dim3(256), 0, stream, ws, acc);
  hipLaunchKernelGGL(kperpoint, dim3(128), dim3(128), 0, stream, pts, lbl, ws, acc);
  hipLaunchKernelGGL(kfused,    dim3(64 + 528 * BB), dim3(256), 0, stream,
                     lbl, (const ushort*)(ws + OFF_EMBH), ws, acc);
  hipLaunchKernelGGL(kfinal,    dim3(1),   dim3(1),    0, stream, acc, out);
}